// Round 8
// baseline (656.475 us; speedup 1.0000x reference)
//
#include <hip/hip_runtime.h>
#include <hip/hip_bf16.h>
#include <hip/hip_fp16.h>
#include <math.h>

constexpr int NN = 50000;   // nodes
constexpr int NE = 800000;  // edges (without self loops)
constexpr int NH = 8;       // heads
constexpr float L2E = 1.44269504f;  // log2(e)
constexpr int SBLK = 256;
constexpr int SGRID = (NN + SBLK - 1) / SBLK;  // 196

typedef __attribute__((ext_vector_type(8))) short bf16x8;
typedef __attribute__((ext_vector_type(4))) float f32x4;

__device__ inline float b2f(unsigned short u) {
  union { unsigned int i; float f; } v;
  v.i = ((unsigned int)u) << 16;
  return v.f;
}

// ---------------------------------------------------------------------------
// degree histograms (real edges only; self-loop handled in epilogues)
__global__ void k_deg(const int* __restrict__ src, const int* __restrict__ dst,
                      int* __restrict__ degout, int* __restrict__ degin) {
  int i = blockIdx.x * blockDim.x + threadIdx.x;
  if (i < NE) {
    atomicAdd(&degout[src[i]], 1);
    atomicAdd(&degin[dst[i]], 1);
  }
}

__global__ void k_inv(const int* __restrict__ degin, float* __restrict__ inv) {
  int i = blockIdx.x * blockDim.x + threadIdx.x;
  if (i < NN) inv[i] = 1.0f / (float)(degin[i] + 1);
}

// ---- hierarchical exclusive scan (3 small kernels, full-device parallel) ----
__global__ void k_scan1(const int* __restrict__ deg, int* __restrict__ bsum) {
  int i = blockIdx.x * SBLK + threadIdx.x;
  int v = (i < NN) ? deg[i] : 0;
#pragma unroll
  for (int off = 32; off; off >>= 1) v += __shfl_down(v, off, 64);
  __shared__ int ws[SBLK / 64];
  if ((threadIdx.x & 63) == 0) ws[threadIdx.x >> 6] = v;
  __syncthreads();
  if (threadIdx.x == 0) {
    int s = 0;
#pragma unroll
    for (int w = 0; w < SBLK / 64; ++w) s += ws[w];
    bsum[blockIdx.x] = s;
  }
}

__global__ void k_scan2(int* __restrict__ bsum) {  // in-place exclusive scan
  __shared__ int ls[256];
  int t = threadIdx.x;
  int v = (t < SGRID) ? bsum[t] : 0;
  ls[t] = v;
  __syncthreads();
  for (int off = 1; off < 256; off <<= 1) {
    int u = (t >= off) ? ls[t - off] : 0;
    __syncthreads();
    ls[t] += u;
    __syncthreads();
  }
  if (t < SGRID) bsum[t] = ls[t] - v;
}

__global__ void k_scan3(const int* __restrict__ deg, const int* __restrict__ bsum,
                        int* __restrict__ base, int* __restrict__ cursor) {
  __shared__ int ls[SBLK];
  int t = threadIdx.x;
  int i = blockIdx.x * SBLK + t;
  int v = (i < NN) ? deg[i] : 0;
  ls[t] = v;
  __syncthreads();
  for (int off = 1; off < SBLK; off <<= 1) {
    int u = (t >= off) ? ls[t - off] : 0;
    __syncthreads();
    ls[t] += u;
    __syncthreads();
  }
  int ex = ls[t] - v + bsum[blockIdx.x];
  if (i < NN) { base[i] = ex; cursor[i] = ex; }
}

// scatter: csr2[cp]=(dst,src) grouped by src; aux[cp]=csc position (dst-grouped).
__global__ void k_scatter(const int* __restrict__ src, const int* __restrict__ dst,
                          int* __restrict__ cursor, int* __restrict__ cursor2,
                          int2* __restrict__ csr2, int* __restrict__ aux) {
  int e = blockIdx.x * blockDim.x + threadIdx.x;
  if (e < NE) {
    int s = src[e], d = dst[e];
    int cp = atomicAdd(&cursor[s], 1);
    int pp = atomicAdd(&cursor2[d], 1);
    csr2[cp] = make_int2(d, s);
    aux[cp] = pp;
  }
}

// ---------------------------------------------------------------------------
// fp32 -> bf16 conversion, 4 elements/thread
__global__ void k_f2b(const float* __restrict__ in, __hip_bfloat16* __restrict__ out,
                      long n4) {
  long i = (long)blockIdx.x * blockDim.x + threadIdx.x;
  if (i >= n4) return;
  float4 v = reinterpret_cast<const float4*>(in)[i];
  ushort4 o;
  o.x = __hip_bfloat16_raw(__float2bfloat16(v.x)).x;
  o.y = __hip_bfloat16_raw(__float2bfloat16(v.y)).x;
  o.z = __hip_bfloat16_raw(__float2bfloat16(v.z)).x;
  o.w = __hip_bfloat16_raw(__float2bfloat16(v.w)).x;
  reinterpret_cast<ushort4*>(out)[i] = o;
}

// convert W1,W2,W3 in a single launch
__global__ void k_f2b3(const float* __restrict__ w1, const float* __restrict__ w2,
                       const float* __restrict__ w3, __hip_bfloat16* __restrict__ o1,
                       __hip_bfloat16* __restrict__ o2, __hip_bfloat16* __restrict__ o3) {
  int i = blockIdx.x * blockDim.x + threadIdx.x;  // float4 index
  const int n1 = 512 * 64 / 4, n2 = 512 * 64 / 4, n3 = 256 * 64 / 4;
  const float* in; __hip_bfloat16* out; int j = i;
  if (j < n1) { in = w1; out = o1; }
  else if ((j -= n1) < n2) { in = w2; out = o2; }
  else if ((j -= n2) < n3) { in = w3; out = o3; }
  else return;
  float4 v = reinterpret_cast<const float4*>(in)[j];
  ushort4 o;
  o.x = __hip_bfloat16_raw(__float2bfloat16(v.x)).x;
  o.y = __hip_bfloat16_raw(__float2bfloat16(v.y)).x;
  o.z = __hip_bfloat16_raw(__float2bfloat16(v.z)).x;
  o.w = __hip_bfloat16_raw(__float2bfloat16(v.w)).x;
  reinterpret_cast<ushort4*>(out)[j] = o;
}

// ---------------------------------------------------------------------------
// q[n,h] = log2(e) * sum_c X[n,c] * U[h,c]   (prescaled for raw v_exp_f32)
__global__ void k_q(const float* __restrict__ X, const float* __restrict__ U,
                    float* __restrict__ q) {
  int n = blockIdx.x * blockDim.x + threadIdx.x;
  if (n >= NN) return;
  float4 xr[16];
  const float4* X4 = reinterpret_cast<const float4*>(X) + (size_t)n * 16;
#pragma unroll
  for (int i = 0; i < 16; ++i) xr[i] = X4[i];
  const float4* U4 = reinterpret_cast<const float4*>(U);
#pragma unroll
  for (int h = 0; h < 8; ++h) {
    float a = 0.f;
#pragma unroll
    for (int i = 0; i < 16; ++i) {
      float4 u = U4[h * 16 + i];
      a = fmaf(xr[i].x, u.x, a);
      a = fmaf(xr[i].y, u.y, a);
      a = fmaf(xr[i].z, u.z, a);
      a = fmaf(xr[i].w, u.w, a);
    }
    q[(size_t)n * 8 + h] = a * L2E;
  }
}

// ---------------------------------------------------------------------------
// P[n, j] = sum_c Xb[n,c] * Wb[j,c]  via MFMA bf16 (K=64 -> 2 k-steps of 32)
template <int JDIM>
__global__ void __launch_bounds__(JDIM / 64 * 64)
k_mfma_gemm(const __hip_bfloat16* __restrict__ Xb,
            const __hip_bfloat16* __restrict__ Wb,
            __hip_bfloat16* __restrict__ Pb) {
  const int lane = threadIdx.x & 63;
  const int w = threadIdx.x >> 6;
  const int m0 = blockIdx.x * 64;
  const int n0 = w * 64;
  const int lr = lane & 15;
  const int lk = lane >> 4;

  const ushort* X = reinterpret_cast<const ushort*>(Xb);
  const ushort* W = reinterpret_cast<const ushort*>(Wb);

  bf16x8 bfr[4][2];
#pragma unroll
  for (int ni = 0; ni < 4; ++ni)
#pragma unroll
    for (int kk = 0; kk < 2; ++kk) {
      int j = n0 + ni * 16 + lr;
      bfr[ni][kk] = *reinterpret_cast<const bf16x8*>(W + (size_t)j * 64 + kk * 32 + lk * 8);
    }

  bf16x8 afr[4][2];
#pragma unroll
  for (int mi = 0; mi < 4; ++mi)
#pragma unroll
    for (int kk = 0; kk < 2; ++kk) {
      int r = m0 + mi * 16 + lr;
      if (r >= NN) r = NN - 1;
      afr[mi][kk] = *reinterpret_cast<const bf16x8*>(X + (size_t)r * 64 + kk * 32 + lk * 8);
    }

  f32x4 acc[4][4] = {};
#pragma unroll
  for (int mi = 0; mi < 4; ++mi)
#pragma unroll
    for (int ni = 0; ni < 4; ++ni)
#pragma unroll
      for (int kk = 0; kk < 2; ++kk)
        acc[mi][ni] = __builtin_amdgcn_mfma_f32_16x16x32_bf16(
            afr[mi][kk], bfr[ni][kk], acc[mi][ni], 0, 0, 0);

#pragma unroll
  for (int mi = 0; mi < 4; ++mi) {
#pragma unroll
    for (int i = 0; i < 4; ++i) {
      int r = m0 + mi * 16 + lk * 4 + i;
      if (r < NN) {
#pragma unroll
        for (int ni = 0; ni < 4; ++ni) {
          int j = n0 + ni * 16 + lr;
          Pb[(size_t)r * JDIM + j] = __float2bfloat16(acc[mi][ni][i]);
        }
      }
    }
  }
}

// ---------------------------------------------------------------------------
// lane = CSR position: a[k] = 8 x f16 of exp(l_h)/sum * inv_count[dst].
__global__ void k_attn(const int2* __restrict__ csr2, const float* __restrict__ q,
                       const float* __restrict__ cvec, const float* __restrict__ inv,
                       uint4* __restrict__ a) {
  int k = blockIdx.x * blockDim.x + threadIdx.x;
  if (k >= NE) return;
  int2 cd = csr2[k];
  int d = cd.x, s = cd.y;

  const float4* q4 = reinterpret_cast<const float4*>(q);
  const float4* c4 = reinterpret_cast<const float4*>(cvec);
  float4 qd0 = q4[2 * d], qd1 = q4[2 * d + 1];
  float4 qs0 = q4[2 * s], qs1 = q4[2 * s + 1];
  float4 c0 = c4[0], c1 = c4[1];

  float e[8];
  e[0] = __builtin_amdgcn_exp2f(qd0.x - qs0.x + c0.x * L2E);
  e[1] = __builtin_amdgcn_exp2f(qd0.y - qs0.y + c0.y * L2E);
  e[2] = __builtin_amdgcn_exp2f(qd0.z - qs0.z + c0.z * L2E);
  e[3] = __builtin_amdgcn_exp2f(qd0.w - qs0.w + c0.w * L2E);
  e[4] = __builtin_amdgcn_exp2f(qd1.x - qs1.x + c1.x * L2E);
  e[5] = __builtin_amdgcn_exp2f(qd1.y - qs1.y + c1.y * L2E);
  e[6] = __builtin_amdgcn_exp2f(qd1.z - qs1.z + c1.z * L2E);
  e[7] = __builtin_amdgcn_exp2f(qd1.w - qs1.w + c1.w * L2E);

  float sum = ((e[0] + e[1]) + (e[2] + e[3])) + ((e[4] + e[5]) + (e[6] + e[7]));
  float r = __builtin_amdgcn_rcpf(sum) * inv[d];

  __half2 h0 = __floats2half2_rn(e[0] * r, e[1] * r);
  __half2 h1 = __floats2half2_rn(e[2] * r, e[3] * r);
  __half2 h2 = __floats2half2_rn(e[4] * r, e[5] * r);
  __half2 h3 = __floats2half2_rn(e[6] * r, e[7] * r);
  uint4 o;
  o.x = *(unsigned int*)&h0;
  o.y = *(unsigned int*)&h1;
  o.z = *(unsigned int*)&h2;
  o.w = *(unsigned int*)&h3;
  a[k] = o;
}

// ---------------------------------------------------------------------------
// Message pass (src-major, NO atomics): lane owns a channel pair; per edge
// compute 2-ch partial and STORE to the edge's CSC slot (contiguous 128B/64B
// segment at a scattered position). msg slot = packed f16 pair.
template <int COUT>
__global__ void k_msg(const int* __restrict__ base, const int* __restrict__ endp,
                      const int* __restrict__ aux, const uint4* __restrict__ a,
                      const __hip_bfloat16* __restrict__ Pb,
                      unsigned int* __restrict__ msg) {
  constexpr int LPN = COUT / 2;   // lanes per node (32 / 16)
  constexpr int NPW = 64 / LPN;   // nodes per wave (2 / 4)
  const int lane = threadIdx.x & 63;
  const long wid = ((long)blockIdx.x * blockDim.x + threadIdx.x) >> 6;
  const int n = (int)(wid * NPW + lane / LPN);
  if (n >= NN) return;
  const int l = lane % LPN;

  const unsigned int* P32 = reinterpret_cast<const unsigned int*>(Pb);
  float p0[NH], p1[NH];
#pragma unroll
  for (int h = 0; h < NH; ++h) {
    unsigned int v = P32[(size_t)n * (NH * LPN) + h * LPN + l];
    p0[h] = b2f((unsigned short)(v & 0xffff));
    p1[h] = b2f((unsigned short)(v >> 16));
  }

  for (int k = base[n], k1 = endp[n]; k < k1; ++k) {
    int pos = aux[k];
    uint4 av = a[k];
    float2 f0 = __half22float2(*(__half2*)&av.x);
    float2 f1 = __half22float2(*(__half2*)&av.y);
    float2 f2 = __half22float2(*(__half2*)&av.z);
    float2 f3 = __half22float2(*(__half2*)&av.w);
    float s0 = 0.f, s1 = 0.f;
    s0 = fmaf(f0.x, p0[0], s0);  s1 = fmaf(f0.x, p1[0], s1);
    s0 = fmaf(f0.y, p0[1], s0);  s1 = fmaf(f0.y, p1[1], s1);
    s0 = fmaf(f1.x, p0[2], s0);  s1 = fmaf(f1.x, p1[2], s1);
    s0 = fmaf(f1.y, p0[3], s0);  s1 = fmaf(f1.y, p1[3], s1);
    s0 = fmaf(f2.x, p0[4], s0);  s1 = fmaf(f2.x, p1[4], s1);
    s0 = fmaf(f2.y, p0[5], s0);  s1 = fmaf(f2.y, p1[5], s1);
    s0 = fmaf(f3.x, p0[6], s0);  s1 = fmaf(f3.x, p1[6], s1);
    s0 = fmaf(f3.y, p0[7], s0);  s1 = fmaf(f3.y, p1[7], s1);
    __half2 hm = __floats2half2_rn(s0, s1);
    msg[(size_t)pos * LPN + l] = *(unsigned int*)&hm;
  }
}

// ---------------------------------------------------------------------------
// Reduce pass (dst-major, coalesced): fp32-accumulate node's contiguous msg
// rows; fuse selfloop + bias + relu + BN-stats. 32 lanes/node, 8 nodes/block.
__global__ void k_redfin(const int* __restrict__ cscbase, const int* __restrict__ cscend,
                         const unsigned int* __restrict__ msg, const float* __restrict__ inv,
                         const float* __restrict__ b, const __hip_bfloat16* __restrict__ Pb,
                         const float* __restrict__ cvec,
                         float* __restrict__ y, float* __restrict__ stats) {
  __shared__ float ssum[64], ssq[64];
  const int t = threadIdx.x;
  if (t < 64) { ssum[t] = 0.f; ssq[t] = 0.f; }
  __syncthreads();

  float wc[8], wsum = 0.f;
#pragma unroll
  for (int h = 0; h < 8; ++h) { wc[h] = __builtin_amdgcn_exp2f(cvec[h] * L2E); wsum += wc[h]; }
  const float rs = __builtin_amdgcn_rcpf(wsum);

  const int l = t & 31;        // channel pair: 2l, 2l+1
  const int sub = t >> 5;      // node slot (0..7)
  const unsigned int* P32 = reinterpret_cast<const unsigned int*>(Pb);
  const float b0 = b[2 * l], b1 = b[2 * l + 1];
  float lsum0 = 0.f, lsq0 = 0.f, lsum1 = 0.f, lsq1 = 0.f;

  for (int n0 = blockIdx.x * 8; n0 < NN; n0 += gridDim.x * 8) {
    int n = n0 + sub;   // NN % 8 == 0
    float s0 = 0.f, s1 = 0.f;
    for (int pos = cscbase[n], p1e = cscend[n]; pos < p1e; ++pos) {
      unsigned int m = msg[(size_t)pos * 32 + l];
      float2 f = __half22float2(*(__half2*)&m);
      s0 += f.x; s1 += f.y;
    }
    float sl0 = 0.f, sl1 = 0.f;
#pragma unroll
    for (int h = 0; h < 8; ++h) {
      unsigned int v = P32[(size_t)n * 256 + h * 32 + l];
      sl0 = fmaf(wc[h], b2f((unsigned short)(v & 0xffff)), sl0);
      sl1 = fmaf(wc[h], b2f((unsigned short)(v >> 16)), sl1);
    }
    float r = rs * inv[n];
    float v0 = fmaxf(fmaf(sl0, r, s0) + b0, 0.f);
    float v1 = fmaxf(fmaf(sl1, r, s1) + b1, 0.f);
    reinterpret_cast<float2*>(y)[(size_t)n * 32 + l] = make_float2(v0, v1);
    lsum0 += v0; lsq0 = fmaf(v0, v0, lsq0);
    lsum1 += v1; lsq1 = fmaf(v1, v1, lsq1);
  }
  atomicAdd(&ssum[2 * l], lsum0);
  atomicAdd(&ssq[2 * l], lsq0);
  atomicAdd(&ssum[2 * l + 1], lsum1);
  atomicAdd(&ssq[2 * l + 1], lsq1);
  __syncthreads();
  if (t < 64) {
    atomicAdd(&stats[t], ssum[t]);
    atomicAdd(&stats[64 + t], ssq[t]);
  }
}

// layer-3 reduce: out = sum(msg) + selfloop + b.  16 lanes/node, 16 nodes/block.
__global__ void k_red3(const int* __restrict__ cscbase, const int* __restrict__ cscend,
                       const unsigned int* __restrict__ msg, const float* __restrict__ inv,
                       const float* __restrict__ b, const __hip_bfloat16* __restrict__ Pb,
                       const float* __restrict__ cvec, float* __restrict__ out) {
  float wc[8], wsum = 0.f;
#pragma unroll
  for (int h = 0; h < 8; ++h) { wc[h] = __builtin_amdgcn_exp2f(cvec[h] * L2E); wsum += wc[h]; }
  const float rs = __builtin_amdgcn_rcpf(wsum);

  const int t = threadIdx.x;
  const int l = t & 15;        // channel pair: 2l, 2l+1
  const int sub = t >> 4;      // node slot (0..15)
  const unsigned int* P32 = reinterpret_cast<const unsigned int*>(Pb);
  const float b0 = b[2 * l], b1 = b[2 * l + 1];

  for (int n0 = blockIdx.x * 16; n0 < NN; n0 += gridDim.x * 16) {
    int n = n0 + sub;   // NN % 16 == 0
    float s0 = 0.f, s1 = 0.f;
    for (int pos = cscbase[n], p1e = cscend[n]; pos < p1e; ++pos) {
      unsigned int m = msg[(size_t)pos * 16 + l];
      float2 f = __half22float2(*(__half2*)&m);
      s0 += f.x; s1 += f.y;
    }
    float sl0 = 0.f, sl1 = 0.f;
#pragma unroll
    for (int h = 0; h < 8; ++h) {
      unsigned int v = P32[(size_t)n * 128 + h * 16 + l];
      sl0 = fmaf(wc[h], b2f((unsigned short)(v & 0xffff)), sl0);
      sl1 = fmaf(wc[h], b2f((unsigned short)(v >> 16)), sl1);
    }
    float r = rs * inv[n];
    reinterpret_cast<float2*>(out)[(size_t)n * 16 + l] =
        make_float2(fmaf(sl0, r, s0) + b0, fmaf(sl1, r, s1) + b1);
  }
}

// BN: writes h (fp32, for next layer's q) and hb (bf16, for MFMA)
__global__ void k_bn(const float* __restrict__ y, const float* __restrict__ stats,
                     const float* __restrict__ g, const float* __restrict__ be,
                     float* __restrict__ h, __hip_bfloat16* __restrict__ hb) {
  long idx = (long)blockIdx.x * blockDim.x + threadIdx.x;
  if (idx >= (long)NN * 64) return;
  int o = (int)(idx & 63);
  float m = stats[o] * (1.0f / NN);
  float v = stats[64 + o] * (1.0f / NN) - m * m;
  float r = fmaf(g[o] * rsqrtf(v + 1e-5f), y[idx] - m, be[o]);
  h[idx] = r;
  hb[idx] = __float2bfloat16(r);
}

// ---------------------------------------------------------------------------
extern "C" void kernel_launch(void* const* d_in, const int* in_sizes, int n_in,
                              void* d_out, int out_size, void* d_ws, size_t ws_size,
                              hipStream_t stream) {
  const float* x   = (const float*)d_in[0];
  const int*   src = (const int*)d_in[1];
  const int*   dst = src + NE;
  const float* W1 = (const float*)d_in[2];
  const float* U1 = (const float*)d_in[3];
  const float* c1 = (const float*)d_in[4];
  const float* b1 = (const float*)d_in[5];
  const float* g1 = (const float*)d_in[6];
  const float* be1 = (const float*)d_in[7];
  const float* W2 = (const float*)d_in[8];
  const float* U2 = (const float*)d_in[9];
  const float* c2 = (const float*)d_in[10];
  const float* b2 = (const float*)d_in[11];
  const float* g2 = (const float*)d_in[12];
  const float* be2 = (const float*)d_in[13];
  const float* W3 = (const float*)d_in[14];
  const float* U3 = (const float*)d_in[15];
  const float* c3 = (const float*)d_in[16];
  const float* b3 = (const float*)d_in[17];
  float* out = (float*)d_out;

  // workspace layout (16B alignment maintained at every section)
  float* ws   = (float*)d_ws;
  float* inv  = ws;                           // N
  float* q    = inv + NN;                     // N*8
  float* h    = q + (size_t)NN * 8;           // N*64
  float* stats = h + (size_t)NN * 64;         // 128
  uint4* a    = (uint4*)(stats + 128);        // NE (16B/edge, f16 attn weights)
  __hip_bfloat16* xb = (__hip_bfloat16*)(a + NE);   // N*64 bf16
  __hip_bfloat16* Wb1 = xb + (size_t)NN * 64;
  __hip_bfloat16* Wb2 = Wb1 + 512 * 64;
  __hip_bfloat16* Wb3 = Wb2 + 512 * 64;
  __hip_bfloat16* Pb = Wb3 + 256 * 64;              // N*512 bf16
  int* degout  = (int*)(Pb + (size_t)NN * 512);     // N
  int* degin   = degout + NN;                       // N
  int* basep   = degin + NN;                        // N
  int* cursor  = basep + NN;                        // N (CSR end after scatter)
  int* cscbase = cursor + NN;                       // N
  int* cursor2 = cscbase + NN;                      // N (CSC end after scatter)
  int* bsum    = cursor2 + NN;                      // 256
  int2* csr2   = (int2*)(bsum + 256);               // NE
  int* aux     = (int*)(csr2 + NE);                 // NE (CSR pos -> CSC pos)
  unsigned int* msg = (unsigned int*)(aux + NE);    // NE*32 (f16-pair slots)

  const int BLK = 256;
  dim3 b256(BLK);

  // ---- CSR + CSC build (once; reused by all 3 layers) ----
  hipMemsetAsync(degout, 0, (size_t)NN * 8, stream);  // degout + degin
  k_deg<<<dim3((NE + BLK - 1) / BLK), b256, 0, stream>>>(src, dst, degout, degin);
  k_inv<<<dim3((NN + BLK - 1) / BLK), b256, 0, stream>>>(degin, inv);
  k_scan1<<<dim3(SGRID), dim3(SBLK), 0, stream>>>(degout, bsum);
  k_scan2<<<dim3(1), dim3(256), 0, stream>>>(bsum);
  k_scan3<<<dim3(SGRID), dim3(SBLK), 0, stream>>>(degout, bsum, basep, cursor);
  k_scan1<<<dim3(SGRID), dim3(SBLK), 0, stream>>>(degin, bsum);
  k_scan2<<<dim3(1), dim3(256), 0, stream>>>(bsum);
  k_scan3<<<dim3(SGRID), dim3(SBLK), 0, stream>>>(degin, bsum, cscbase, cursor2);
  k_scatter<<<dim3((NE + BLK - 1) / BLK), b256, 0, stream>>>(src, dst, cursor, cursor2, csr2, aux);

  const int qgrid = (NN + BLK - 1) / BLK;
  const int mfma_grid = (NN + 63) / 64;
  const int attn_grid = (NE + BLK - 1) / BLK;
  const int msg_grid64 = NN / 8;    // 2 nodes/wave, 8/block
  const int msg_grid32 = NN / 16;   // 4 nodes/wave, 16/block
  const long xb4 = (long)NN * 64 / 4;
  const int w3grid = ((512 * 64 / 4) * 2 + (256 * 64 / 4) + BLK - 1) / BLK;

  // one-time conversions
  k_f2b<<<dim3((xb4 + BLK - 1) / BLK), b256, 0, stream>>>(x, xb, xb4);
  k_f2b3<<<dim3(w3grid), b256, 0, stream>>>(W1, W2, W3, Wb1, Wb2, Wb3);

  // ---- layer 1: x -> h ----
  k_q<<<dim3(qgrid), b256, 0, stream>>>(x, U1, q);
  k_mfma_gemm<512><<<dim3(mfma_grid), dim3(512), 0, stream>>>(xb, Wb1, Pb);
  k_attn<<<dim3(attn_grid), b256, 0, stream>>>(csr2, q, c1, inv, a);
  hipMemsetAsync(stats, 0, 128 * 4, stream);
  k_msg<64><<<dim3(msg_grid64), b256, 0, stream>>>(basep, cursor, aux, a, Pb, msg);
  k_redfin<<<dim3(2048), b256, 0, stream>>>(cscbase, cursor2, msg, inv, b1, Pb, c1, h, stats);
  k_bn<<<dim3(((size_t)NN * 64 + BLK - 1) / BLK), b256, 0, stream>>>(h, stats, g1, be1, h, xb);

  // ---- layer 2: h -> h ----
  k_q<<<dim3(qgrid), b256, 0, stream>>>(h, U2, q);
  k_mfma_gemm<512><<<dim3(mfma_grid), dim3(512), 0, stream>>>(xb, Wb2, Pb);
  k_attn<<<dim3(attn_grid), b256, 0, stream>>>(csr2, q, c2, inv, a);
  hipMemsetAsync(stats, 0, 128 * 4, stream);
  k_msg<64><<<dim3(msg_grid64), b256, 0, stream>>>(basep, cursor, aux, a, Pb, msg);
  k_redfin<<<dim3(2048), b256, 0, stream>>>(cscbase, cursor2, msg, inv, b2, Pb, c2, h, stats);
  k_bn<<<dim3(((size_t)NN * 64 + BLK - 1) / BLK), b256, 0, stream>>>(h, stats, g2, be2, h, xb);

  // ---- layer 3: h -> out ----
  k_q<<<dim3(qgrid), b256, 0, stream>>>(h, U3, q);
  k_mfma_gemm<256><<<dim3(mfma_grid), dim3(256), 0, stream>>>(xb, Wb3, Pb);
  k_attn<<<dim3(attn_grid), b256, 0, stream>>>(csr2, q, c3, inv, a);
  k_msg<32><<<dim3(msg_grid32), b256, 0, stream>>>(basep, cursor, aux, a, Pb, msg);
  k_red3<<<dim3(1024), b256, 0, stream>>>(cscbase, cursor2, msg, inv, b3, Pb, c3, out);
}

// Round 9
// 561.587 us; speedup vs baseline: 1.1690x; 1.1690x over previous
//
#include <hip/hip_runtime.h>
#include <hip/hip_bf16.h>
#include <hip/hip_fp16.h>
#include <math.h>

constexpr int NN = 50000;   // nodes
constexpr int NE = 800000;  // edges (without self loops)
constexpr int NH = 8;       // heads
constexpr float L2E = 1.44269504f;  // log2(e)
constexpr int SBLK = 256;
constexpr int SGRID = (NN + SBLK - 1) / SBLK;  // 196

typedef __attribute__((ext_vector_type(8))) short bf16x8;
typedef __attribute__((ext_vector_type(4))) float f32x4;

__device__ inline float b2f(unsigned short u) {
  union { unsigned int i; float f; } v;
  v.i = ((unsigned int)u) << 16;
  return v.f;
}

// ---------------------------------------------------------------------------
// in-degree histogram (real edges only; self-loop handled inside k_zagg)
__global__ void k_deg(const int* __restrict__ dst, int* __restrict__ degin) {
  int i = blockIdx.x * blockDim.x + threadIdx.x;
  if (i < NE) atomicAdd(&degin[dst[i]], 1);
}

__global__ void k_inv(const int* __restrict__ degin, float* __restrict__ inv) {
  int i = blockIdx.x * blockDim.x + threadIdx.x;
  if (i < NN) inv[i] = 1.0f / (float)(degin[i] + 1);
}

// ---- hierarchical exclusive scan (3 small kernels) ----
__global__ void k_scan1(const int* __restrict__ deg, int* __restrict__ bsum) {
  int i = blockIdx.x * SBLK + threadIdx.x;
  int v = (i < NN) ? deg[i] : 0;
#pragma unroll
  for (int off = 32; off; off >>= 1) v += __shfl_down(v, off, 64);
  __shared__ int ws[SBLK / 64];
  if ((threadIdx.x & 63) == 0) ws[threadIdx.x >> 6] = v;
  __syncthreads();
  if (threadIdx.x == 0) {
    int s = 0;
#pragma unroll
    for (int w = 0; w < SBLK / 64; ++w) s += ws[w];
    bsum[blockIdx.x] = s;
  }
}

__global__ void k_scan2(int* __restrict__ bsum) {
  __shared__ int ls[256];
  int t = threadIdx.x;
  int v = (t < SGRID) ? bsum[t] : 0;
  ls[t] = v;
  __syncthreads();
  for (int off = 1; off < 256; off <<= 1) {
    int u = (t >= off) ? ls[t - off] : 0;
    __syncthreads();
    ls[t] += u;
    __syncthreads();
  }
  if (t < SGRID) bsum[t] = ls[t] - v;
}

__global__ void k_scan3(const int* __restrict__ deg, const int* __restrict__ bsum,
                        int* __restrict__ base, int* __restrict__ cursor) {
  __shared__ int ls[SBLK];
  int t = threadIdx.x;
  int i = blockIdx.x * SBLK + t;
  int v = (i < NN) ? deg[i] : 0;
  ls[t] = v;
  __syncthreads();
  for (int off = 1; off < SBLK; off <<= 1) {
    int u = (t >= off) ? ls[t - off] : 0;
    __syncthreads();
    ls[t] += u;
    __syncthreads();
  }
  int ex = ls[t] - v + bsum[blockIdx.x];
  if (i < NN) { base[i] = ex; cursor[i] = ex; }
}

// scatter: csc2[pos] = (src, dst), grouped by dst. One atomic per edge.
__global__ void k_scatter(const int* __restrict__ src, const int* __restrict__ dst,
                          int* __restrict__ cursor, int2* __restrict__ csc2) {
  int e = blockIdx.x * blockDim.x + threadIdx.x;
  if (e < NE) {
    int s = src[e], d = dst[e];
    int pos = atomicAdd(&cursor[d], 1);
    csc2[pos] = make_int2(s, d);
  }
}

// ---------------------------------------------------------------------------
// fp32 -> bf16 conversion, 4 elements/thread
__global__ void k_f2b(const float* __restrict__ in, __hip_bfloat16* __restrict__ out,
                      long n4) {
  long i = (long)blockIdx.x * blockDim.x + threadIdx.x;
  if (i >= n4) return;
  float4 v = reinterpret_cast<const float4*>(in)[i];
  ushort4 o;
  o.x = __hip_bfloat16_raw(__float2bfloat16(v.x)).x;
  o.y = __hip_bfloat16_raw(__float2bfloat16(v.y)).x;
  o.z = __hip_bfloat16_raw(__float2bfloat16(v.z)).x;
  o.w = __hip_bfloat16_raw(__float2bfloat16(v.w)).x;
  reinterpret_cast<ushort4*>(out)[i] = o;
}

// build W''[o][h*64+c] = W[h*Cout+o][c] as bf16, for the 3 layers in one launch
__global__ void k_wt(const float* __restrict__ w1, const float* __restrict__ w2,
                     const float* __restrict__ w3, __hip_bfloat16* __restrict__ t1,
                     __hip_bfloat16* __restrict__ t2, __hip_bfloat16* __restrict__ t3) {
  int i = blockIdx.x * blockDim.x + threadIdx.x;
  const int n1 = 64 * 512, n2 = 64 * 512, n3 = 32 * 512;
  const float* w; __hip_bfloat16* t; int cout; int j = i;
  if (j < n1) { w = w1; t = t1; cout = 64; }
  else if ((j -= n1) < n2) { w = w2; t = t2; cout = 64; }
  else if ((j -= n2) < n3) { w = w3; t = t3; cout = 32; }
  else return;
  int o = j >> 9;          // output channel
  int hc = j & 511;
  int h = hc >> 6, c = hc & 63;
  t[j] = __float2bfloat16(w[(h * cout + o) * 64 + c]);
}

// ---------------------------------------------------------------------------
// q[n,h] = log2(e) * sum_c X[n,c] * U[h,c]   (prescaled for raw v_exp_f32)
__global__ void k_q(const float* __restrict__ X, const float* __restrict__ U,
                    float* __restrict__ q) {
  int n = blockIdx.x * blockDim.x + threadIdx.x;
  if (n >= NN) return;
  float4 xr[16];
  const float4* X4 = reinterpret_cast<const float4*>(X) + (size_t)n * 16;
#pragma unroll
  for (int i = 0; i < 16; ++i) xr[i] = X4[i];
  const float4* U4 = reinterpret_cast<const float4*>(U);
#pragma unroll
  for (int h = 0; h < 8; ++h) {
    float a = 0.f;
#pragma unroll
    for (int i = 0; i < 16; ++i) {
      float4 u = U4[h * 16 + i];
      a = fmaf(xr[i].x, u.x, a);
      a = fmaf(xr[i].y, u.y, a);
      a = fmaf(xr[i].z, u.z, a);
      a = fmaf(xr[i].w, u.w, a);
    }
    q[(size_t)n * 8 + h] = a * L2E;
  }
}

// ---------------------------------------------------------------------------
// lane = CSC position: a[k] = 8 x f16 of exp(l_h)/sum * inv_count[dst].
__global__ void k_attn(const int2* __restrict__ csc2, const float* __restrict__ q,
                       const float* __restrict__ cvec, const float* __restrict__ inv,
                       uint4* __restrict__ a) {
  int k = blockIdx.x * blockDim.x + threadIdx.x;
  if (k >= NE) return;
  int2 sd = csc2[k];
  int s = sd.x, d = sd.y;

  const float4* q4 = reinterpret_cast<const float4*>(q);
  const float4* c4 = reinterpret_cast<const float4*>(cvec);
  float4 qd0 = q4[2 * d], qd1 = q4[2 * d + 1];
  float4 qs0 = q4[2 * s], qs1 = q4[2 * s + 1];
  float4 c0 = c4[0], c1 = c4[1];

  float e[8];
  e[0] = __builtin_amdgcn_exp2f(qd0.x - qs0.x + c0.x * L2E);
  e[1] = __builtin_amdgcn_exp2f(qd0.y - qs0.y + c0.y * L2E);
  e[2] = __builtin_amdgcn_exp2f(qd0.z - qs0.z + c0.z * L2E);
  e[3] = __builtin_amdgcn_exp2f(qd0.w - qs0.w + c0.w * L2E);
  e[4] = __builtin_amdgcn_exp2f(qd1.x - qs1.x + c1.x * L2E);
  e[5] = __builtin_amdgcn_exp2f(qd1.y - qs1.y + c1.y * L2E);
  e[6] = __builtin_amdgcn_exp2f(qd1.z - qs1.z + c1.z * L2E);
  e[7] = __builtin_amdgcn_exp2f(qd1.w - qs1.w + c1.w * L2E);

  float sum = ((e[0] + e[1]) + (e[2] + e[3])) + ((e[4] + e[5]) + (e[6] + e[7]));
  float r = __builtin_amdgcn_rcpf(sum) * inv[d];

  __half2 h0 = __floats2half2_rn(e[0] * r, e[1] * r);
  __half2 h1 = __floats2half2_rn(e[2] * r, e[3] * r);
  __half2 h2 = __floats2half2_rn(e[4] * r, e[5] * r);
  __half2 h3 = __floats2half2_rn(e[6] * r, e[7] * r);
  uint4 o;
  o.x = *(unsigned int*)&h0;
  o.y = *(unsigned int*)&h1;
  o.z = *(unsigned int*)&h2;
  o.w = *(unsigned int*)&h3;
  a[k] = o;
}

// ---------------------------------------------------------------------------
// z-aggregation (dst-major, NO atomics): wave = dst node, lane = input channel.
// z[h][lane] = selfloop + sum_in-edges a[k][h] * x_src[lane]. Write bf16 z row.
__global__ void k_zagg(const int* __restrict__ cscbase, const int* __restrict__ cscend,
                       const int2* __restrict__ csc2, const uint4* __restrict__ a,
                       const ushort* __restrict__ xb, const float* __restrict__ inv,
                       const float* __restrict__ cvec, __hip_bfloat16* __restrict__ zb) {
  const int lane = threadIdx.x & 63;
  const int n = (int)(((long)blockIdx.x * blockDim.x + threadIdx.x) >> 6);
  if (n >= NN) return;

  // self-loop init: z[h] = softmax(c)[h] * inv[n] * x_n[lane]
  float wc[8], wsum = 0.f;
#pragma unroll
  for (int h = 0; h < 8; ++h) { wc[h] = __builtin_amdgcn_exp2f(cvec[h] * L2E); wsum += wc[h]; }
  const float rs = __builtin_amdgcn_rcpf(wsum) * inv[n];
  const float xd = b2f(xb[(size_t)n * 64 + lane]);
  float z[8];
#pragma unroll
  for (int h = 0; h < 8; ++h) z[h] = wc[h] * rs * xd;

  for (int k = cscbase[n], k1 = cscend[n]; k < k1; ++k) {
    int s = csc2[k].x;
    uint4 av = a[k];
    float2 f0 = __half22float2(*(__half2*)&av.x);
    float2 f1 = __half22float2(*(__half2*)&av.y);
    float2 f2 = __half22float2(*(__half2*)&av.z);
    float2 f3 = __half22float2(*(__half2*)&av.w);
    float xs = b2f(xb[(size_t)s * 64 + lane]);
    z[0] = fmaf(f0.x, xs, z[0]);
    z[1] = fmaf(f0.y, xs, z[1]);
    z[2] = fmaf(f1.x, xs, z[2]);
    z[3] = fmaf(f1.y, xs, z[3]);
    z[4] = fmaf(f2.x, xs, z[4]);
    z[5] = fmaf(f2.y, xs, z[5]);
    z[6] = fmaf(f3.x, xs, z[6]);
    z[7] = fmaf(f3.y, xs, z[7]);
  }

  ushort* zo = reinterpret_cast<ushort*>(zb) + (size_t)n * 512 + lane;
#pragma unroll
  for (int h = 0; h < 8; ++h)
    zo[h * 64] = __hip_bfloat16_raw(__float2bfloat16(z[h])).x;
}

// ---------------------------------------------------------------------------
// go[m][j] = sum_k zb[m][k] * Wt[j][k]   (K=512). 4 waves/block, wave = 64-row
// m-tile; MFMA 16x16x32 bf16, verified C/D mapping.
template <int JOUT>
__global__ void __launch_bounds__(256)
k_zgemm(const __hip_bfloat16* __restrict__ Zb, const __hip_bfloat16* __restrict__ Wt,
        float* __restrict__ go) {
  const int lane = threadIdx.x & 63;
  const int w = threadIdx.x >> 6;
  const int m0 = (blockIdx.x * 4 + w) * 64;
  const int lr = lane & 15;
  const int lk = lane >> 4;
  constexpr int NT = JOUT / 16;

  const ushort* Z = reinterpret_cast<const ushort*>(Zb);
  const ushort* W = reinterpret_cast<const ushort*>(Wt);

  f32x4 acc[4][NT] = {};
  for (int kk = 0; kk < 16; ++kk) {
    bf16x8 bfr[NT];
#pragma unroll
    for (int ni = 0; ni < NT; ++ni) {
      int j = ni * 16 + lr;
      bfr[ni] = *reinterpret_cast<const bf16x8*>(W + (size_t)j * 512 + kk * 32 + lk * 8);
    }
#pragma unroll
    for (int mi = 0; mi < 4; ++mi) {
      int r = m0 + mi * 16 + lr;
      if (r >= NN) r = NN - 1;
      bf16x8 afr = *reinterpret_cast<const bf16x8*>(Z + (size_t)r * 512 + kk * 32 + lk * 8);
#pragma unroll
      for (int ni = 0; ni < NT; ++ni)
        acc[mi][ni] = __builtin_amdgcn_mfma_f32_16x16x32_bf16(afr, bfr[ni], acc[mi][ni], 0, 0, 0);
    }
  }

#pragma unroll
  for (int mi = 0; mi < 4; ++mi) {
#pragma unroll
    for (int i = 0; i < 4; ++i) {
      int r = m0 + mi * 16 + lk * 4 + i;
      if (r < NN) {
#pragma unroll
        for (int ni = 0; ni < NT; ++ni)
          go[(size_t)r * JOUT + ni * 16 + lr] = acc[mi][ni][i];
      }
    }
  }
}

// ---------------------------------------------------------------------------
// y = relu(go + b); accumulate per-channel sum/sumsq into stats
__global__ void k_finalize_relu(const float* __restrict__ go, const float* __restrict__ b,
                                float* __restrict__ y, float* __restrict__ stats) {
  __shared__ float ssum[64], ssq[64];
  const int t = threadIdx.x;
  if (t < 64) { ssum[t] = 0.f; ssq[t] = 0.f; }
  __syncthreads();

  const int o = t & 63;
  const float bo = b[o];
  float lsum = 0.f, lsq = 0.f;
  for (long idx = (long)blockIdx.x * blockDim.x + threadIdx.x; idx < (long)NN * 64;
       idx += (long)gridDim.x * blockDim.x) {
    float v = fmaxf(go[idx] + bo, 0.f);
    y[idx] = v;
    lsum += v;
    lsq = fmaf(v, v, lsq);
  }
  atomicAdd(&ssum[o], lsum);
  atomicAdd(&ssq[o], lsq);
  __syncthreads();
  if (t < 64) {
    atomicAdd(&stats[t], ssum[t]);
    atomicAdd(&stats[64 + t], ssq[t]);
  }
}

// BN: writes h (fp32, for next layer's q) and hb (bf16, for z-gather/MFMA)
__global__ void k_bn(const float* __restrict__ y, const float* __restrict__ stats,
                     const float* __restrict__ g, const float* __restrict__ be,
                     float* __restrict__ h, __hip_bfloat16* __restrict__ hb) {
  long idx = (long)blockIdx.x * blockDim.x + threadIdx.x;
  if (idx >= (long)NN * 64) return;
  int o = (int)(idx & 63);
  float m = stats[o] * (1.0f / NN);
  float v = stats[64 + o] * (1.0f / NN) - m * m;
  float r = fmaf(g[o] * rsqrtf(v + 1e-5f), y[idx] - m, be[o]);
  h[idx] = r;
  hb[idx] = __float2bfloat16(r);
}

// layer-3 epilogue: out = go + b
__global__ void k_final3(const float* __restrict__ go, const float* __restrict__ b,
                         float* __restrict__ out) {
  long idx = (long)blockIdx.x * blockDim.x + threadIdx.x;
  if (idx >= (long)NN * 32) return;
  out[idx] = go[idx] + b[(int)(idx & 31)];
}

// ---------------------------------------------------------------------------
extern "C" void kernel_launch(void* const* d_in, const int* in_sizes, int n_in,
                              void* d_out, int out_size, void* d_ws, size_t ws_size,
                              hipStream_t stream) {
  const float* x   = (const float*)d_in[0];
  const int*   src = (const int*)d_in[1];
  const int*   dst = src + NE;
  const float* W1 = (const float*)d_in[2];
  const float* U1 = (const float*)d_in[3];
  const float* c1 = (const float*)d_in[4];
  const float* b1 = (const float*)d_in[5];
  const float* g1 = (const float*)d_in[6];
  const float* be1 = (const float*)d_in[7];
  const float* W2 = (const float*)d_in[8];
  const float* U2 = (const float*)d_in[9];
  const float* c2 = (const float*)d_in[10];
  const float* b2 = (const float*)d_in[11];
  const float* g2 = (const float*)d_in[12];
  const float* be2 = (const float*)d_in[13];
  const float* W3 = (const float*)d_in[14];
  const float* U3 = (const float*)d_in[15];
  const float* c3 = (const float*)d_in[16];
  const float* b3 = (const float*)d_in[17];
  float* out = (float*)d_out;

  // workspace layout (16B alignment maintained)
  float* ws   = (float*)d_ws;
  float* inv  = ws;                           // N
  float* q    = inv + NN;                     // N*8
  float* h    = q + (size_t)NN * 8;           // N*64
  float* go   = h + (size_t)NN * 64;          // N*64 (gemm out fp32)
  float* stats = go + (size_t)NN * 64;        // 128
  uint4* a    = (uint4*)(stats + 128);        // NE (16B/edge f16 attn weights)
  __hip_bfloat16* xb = (__hip_bfloat16*)(a + NE);   // N*64 bf16
  __hip_bfloat16* zb = xb + (size_t)NN * 64;        // N*512 bf16
  __hip_bfloat16* Wt1 = zb + (size_t)NN * 512;      // 64*512 bf16
  __hip_bfloat16* Wt2 = Wt1 + 64 * 512;             // 64*512 bf16
  __hip_bfloat16* Wt3 = Wt2 + 64 * 512;             // 32*512 bf16
  int* degin   = (int*)(Wt3 + 32 * 512);            // N
  int* cscbase = degin + NN;                        // N
  int* cursor  = cscbase + NN;                      // N (CSC end after scatter)
  int* bsum    = cursor + NN;                       // 256
  int2* csc2   = (int2*)(bsum + 256);               // NE

  const int BLK = 256;
  dim3 b256(BLK);

  // ---- CSC build (once; reused by all 3 layers) ----
  hipMemsetAsync(degin, 0, (size_t)NN * 4, stream);
  k_deg<<<dim3((NE + BLK - 1) / BLK), b256, 0, stream>>>(dst, degin);
  k_inv<<<dim3((NN + BLK - 1) / BLK), b256, 0, stream>>>(degin, inv);
  k_scan1<<<dim3(SGRID), dim3(SBLK), 0, stream>>>(degin, bsum);
  k_scan2<<<dim3(1), dim3(256), 0, stream>>>(bsum);
  k_scan3<<<dim3(SGRID), dim3(SBLK), 0, stream>>>(degin, bsum, cscbase, cursor);
  k_scatter<<<dim3((NE + BLK - 1) / BLK), b256, 0, stream>>>(src, dst, cursor, csc2);

  const int qgrid = (NN + BLK - 1) / BLK;
  const int attn_grid = (NE + BLK - 1) / BLK;
  const int zagg_grid = NN * 64 / BLK;             // 12500, NN*64 % 256 == 0
  const int zgemm_grid = (NN + 255) / 256;         // 196 (4 waves x 64 rows)
  const long xb4 = (long)NN * 64 / 4;
  const int wtgrid = (64 * 512 * 2 + 32 * 512 + BLK - 1) / BLK;

  // one-time conversions
  k_f2b<<<dim3((xb4 + BLK - 1) / BLK), b256, 0, stream>>>(x, xb, xb4);
  k_wt<<<dim3(wtgrid), b256, 0, stream>>>(W1, W2, W3, Wt1, Wt2, Wt3);

  // ---- layer 1: x -> h ----
  k_q<<<dim3(qgrid), b256, 0, stream>>>(x, U1, q);
  k_attn<<<dim3(attn_grid), b256, 0, stream>>>(csc2, q, c1, inv, a);
  k_zagg<<<dim3(zagg_grid), b256, 0, stream>>>(cscbase, cursor, csc2, a,
                                               (const ushort*)xb, inv, c1, zb);
  k_zgemm<64><<<dim3(zgemm_grid), b256, 0, stream>>>(zb, Wt1, go);
  hipMemsetAsync(stats, 0, 128 * 4, stream);
  k_finalize_relu<<<dim3(1024), b256, 0, stream>>>(go, b1, go, stats);
  k_bn<<<dim3(((size_t)NN * 64 + BLK - 1) / BLK), b256, 0, stream>>>(go, stats, g1, be1, h, xb);

  // ---- layer 2: h -> h ----
  k_q<<<dim3(qgrid), b256, 0, stream>>>(h, U2, q);
  k_attn<<<dim3(attn_grid), b256, 0, stream>>>(csc2, q, c2, inv, a);
  k_zagg<<<dim3(zagg_grid), b256, 0, stream>>>(cscbase, cursor, csc2, a,
                                               (const ushort*)xb, inv, c2, zb);
  k_zgemm<64><<<dim3(zgemm_grid), b256, 0, stream>>>(zb, Wt2, go);
  hipMemsetAsync(stats, 0, 128 * 4, stream);
  k_finalize_relu<<<dim3(1024), b256, 0, stream>>>(go, b2, go, stats);
  k_bn<<<dim3(((size_t)NN * 64 + BLK - 1) / BLK), b256, 0, stream>>>(go, stats, g2, be2, h, xb);

  // ---- layer 3: h -> out ----
  k_q<<<dim3(qgrid), b256, 0, stream>>>(h, U3, q);
  k_attn<<<dim3(attn_grid), b256, 0, stream>>>(csc2, q, c3, inv, a);
  k_zagg<<<dim3(zagg_grid), b256, 0, stream>>>(cscbase, cursor, csc2, a,
                                               (const ushort*)xb, inv, c3, zb);
  k_zgemm<32><<<dim3(zgemm_grid), b256, 0, stream>>>(zb, Wt3, go);
  k_final3<<<dim3(((size_t)NN * 32 + BLK - 1) / BLK), b256, 0, stream>>>(go, b3, out);
}